// Round 5
// baseline (406.054 us; speedup 1.0000x reference)
//
#include <hip/hip_runtime.h>
#include <math.h>

#define STR 12   // LDS row stride (floats): 48B rows -> every row 16B-aligned (ds_*_b128 legal);
                 // 8 consecutive row starts hit banks {0,12,24,4,16,28,8,20} -> all 32 banks, conflict-free

struct Params {
    const float* x;
    const int*   samp1;
    const int*   samp2;
    const int*   samp3;
    const float* pe_w; const float* pe_b;
    const float* qw; const float* qb;
    const float* kw; const float* kb;
    const float* vw; const float* vb;
    const float* ow; const float* ob;
    const float* f1w; const float* f1b;
    const float* f2w; const float* f2b;
    const float* ln1g; const float* ln1b;
    const float* ln2g; const float* ln2b;
    const float* sp1w1; const float* sp1b1; const float* sp1w2; const float* sp1b2;
    const float* sp2w1; const float* sp2b1; const float* sp2w2; const float* sp2b2;
    const float* dr_w; const float* dr_b;
    const float* fc1w; const float* fc1b;
    const float* fc2w; const float* fc2b;
    const float* fow;  const float* fob;
    const float* part;    // ws: 256 blocks x {max, min}
    float* out;
};

__global__ __launch_bounds__(256) void minmax_part(const float4* __restrict__ x4, int n4,
                                                   float* __restrict__ part) {
    float mx = -INFINITY, mn = INFINITY;
    for (int i = blockIdx.x * blockDim.x + threadIdx.x; i < n4; i += gridDim.x * blockDim.x) {
        float4 v = x4[i];
        mx = fmaxf(fmaxf(fmaxf(mx, v.x), fmaxf(v.y, v.z)), v.w);
        mn = fminf(fminf(fminf(mn, v.x), fminf(v.y, v.z)), v.w);
    }
#pragma unroll
    for (int o = 32; o; o >>= 1) {
        mx = fmaxf(mx, __shfl_xor(mx, o));
        mn = fminf(mn, __shfl_xor(mn, o));
    }
    __shared__ float smx[4], smn[4];
    if ((threadIdx.x & 63) == 0) { smx[threadIdx.x >> 6] = mx; smn[threadIdx.x >> 6] = mn; }
    __syncthreads();
    if (threadIdx.x == 0) {
        for (int w = 1; w < 4; ++w) { mx = fmaxf(mx, smx[w]); mn = fminf(mn, smn[w]); }
        part[blockIdx.x * 2]     = mx;
        part[blockIdx.x * 2 + 1] = mn;
    }
}

__device__ __forceinline__ float dot8(const float4& a, const float4& b,
                                      const float4& c, const float4& d) {
    return a.x*c.x + a.y*c.y + a.z*c.z + a.w*c.w
         + b.x*d.x + b.y*d.y + b.z*d.z + b.w*d.w;
}

// One transformer layer, compile-time geometry. Scores/softmax/upd live in
// registers (8-lane group per selected row); LDS only holds h/k/v rows,
// keys (rank phase, aliased as softpool-score buffer), q_sel, upd, vmean.
template<int L, int USAMP, int U, bool POOL>
__device__ __forceinline__ void layer_fn(
    const int t,
    float* __restrict__ h, float* __restrict__ ks, float* __restrict__ vs,
    unsigned long long* __restrict__ keys, float* __restrict__ q_sel,
    float* __restrict__ upd, float* __restrict__ vmean, int* __restrict__ ntop,
    const float* qw, const float* qb, const float* kw, const float* kb,
    const float* vw, const float* vb, const float* ow, const float* ob,
    const float* f1w, const float* f1b, const float* f2w, const float* f2b,
    const float* g1, const float* bb1, const float* g2, const float* bb2,
    const int* __restrict__ samp,
    const float* spw1, const float* spb1, const float* spw2, const float* spb2)
{
    if (t == 0) *ntop = 0;

    float hrr[8], qr[8];
    // ---- projections: k,v -> LDS (b128x2 each); q stays in registers
    if (t < L) {
        const float4 ha = *(const float4*)&h[t*STR];
        const float4 hb = *(const float4*)&h[t*STR+4];
        hrr[0]=ha.x; hrr[1]=ha.y; hrr[2]=ha.z; hrr[3]=ha.w;
        hrr[4]=hb.x; hrr[5]=hb.y; hrr[6]=hb.z; hrr[7]=hb.w;
        float ka[8], va[8];
#pragma unroll
        for (int dd = 0; dd < 8; ++dd) {
            float aq = 0.f, ak = 0.f, av = 0.f;
#pragma unroll
            for (int e = 0; e < 8; ++e) {
                aq += hrr[e] * qw[e*8+dd];
                ak += hrr[e] * kw[e*8+dd];
                av += hrr[e] * vw[e*8+dd];
            }
            qr[dd] = aq + qb[dd];
            ka[dd] = ak + kb[dd];
            va[dd] = av + vb[dd];
        }
        *(float4*)&ks[t*STR]   = make_float4(ka[0],ka[1],ka[2],ka[3]);
        *(float4*)&ks[t*STR+4] = make_float4(ka[4],ka[5],ka[6],ka[7]);
        *(float4*)&vs[t*STR]   = make_float4(va[0],va[1],va[2],va[3]);
        *(float4*)&vs[t*STR+4] = make_float4(va[4],va[5],va[6],va[7]);
    }
    __syncthreads();

    // ---- sparsity measure -> sortable key
    if (t < L) {
        const int* srow = samp + t * USAMP;
        float mx = -INFINITY, sum = 0.f;
#pragma unroll 5
        for (int j = 0; j < USAMP; ++j) {
            const int idx = srow[j];
            const float4 ka = *(const float4*)&ks[idx*STR];
            const float4 kb = *(const float4*)&ks[idx*STR+4];
            const float acc = qr[0]*ka.x + qr[1]*ka.y + qr[2]*ka.z + qr[3]*ka.w
                            + qr[4]*kb.x + qr[5]*kb.y + qr[6]*kb.z + qr[7]*kb.w;
            mx = fmaxf(mx, acc);
            sum += acc;
        }
        const float M = mx - sum / (float)USAMP;
        unsigned ub = __float_as_uint(M);
        ub = (ub & 0x80000000u) ? ~ub : (ub | 0x80000000u);      // order-preserving
        keys[t] = ((unsigned long long)ub << 32)
                | (unsigned long long)(0xFFFFFFFFu - (unsigned)t);   // tie -> lower idx
        if ((L & 1) && t == 0) keys[L] = 0ull;                   // pad for pair reads
    }
    __syncthreads();

    // ---- rank-select top-U via pair reads (b128); keys distinct -> exactly U
    int sj = -1;
    if (t < L) {
        const unsigned long long mykey = keys[t];
        constexpr int NP = (L + 1) / 2;
        const ulonglong2* k2 = (const ulonglong2*)keys;
        int rank = 0;
#pragma unroll 8
        for (int jp = 0; jp < NP; ++jp) {
            const ulonglong2 kk = k2[jp];
            rank += (kk.x > mykey) ? 1 : 0;
            rank += (kk.y > mykey) ? 1 : 0;
        }
        if (rank < U) {
            sj = atomicAdd(ntop, 1);
            *(float4*)&q_sel[sj*STR]   = make_float4(qr[0],qr[1],qr[2],qr[3]);
            *(float4*)&q_sel[sj*STR+4] = make_float4(qr[4],qr[5],qr[6],qr[7]);
        }
    }
    __syncthreads();

    // ---- attention: waves 0..2 = 8-lane group per row j (j = w*8+g < NG);
    //      wave 3 = vmean (+ row 24 whole-wave when U == 25). All in registers.
    {
        const int w = t >> 6;
        constexpr int NG = (U > 24) ? 24 : U;
        if (w < 3) {
            const int g  = (t >> 3) & 7;
            const int lg = t & 7;
            const int j  = w * 8 + g;
            if (j < NG) {
                const float4 qa = *(const float4*)&q_sel[j*STR];
                const float4 qb4 = *(const float4*)&q_sel[j*STR+4];
                constexpr int NK = (L + 7) / 8;
                float pk[NK];
                float mx = -INFINITY;
#pragma unroll
                for (int k = 0; k < NK; ++k) {
                    const int l = lg + 8*k;
                    float s = -INFINITY;
                    if (l < L) {
                        const float4 ka = *(const float4*)&ks[l*STR];
                        const float4 kb = *(const float4*)&ks[l*STR+4];
                        s = dot8(qa, qb4, ka, kb) * 0.35355339059327373f;
                    }
                    pk[k] = s;
                    mx = fmaxf(mx, s);
                }
                mx = fmaxf(mx, __shfl_xor(mx, 1, 8));
                mx = fmaxf(mx, __shfl_xor(mx, 2, 8));
                mx = fmaxf(mx, __shfl_xor(mx, 4, 8));
                float acc[8] = {0,0,0,0,0,0,0,0};
                float ssum = 0.f;
#pragma unroll
                for (int k = 0; k < NK; ++k) {
                    const int l = lg + 8*k;
                    if (l < L) {
                        const float e = __expf(pk[k] - mx);
                        ssum += e;
                        const float4 va = *(const float4*)&vs[l*STR];
                        const float4 vb = *(const float4*)&vs[l*STR+4];
                        acc[0] += e*va.x; acc[1] += e*va.y; acc[2] += e*va.z; acc[3] += e*va.w;
                        acc[4] += e*vb.x; acc[5] += e*vb.y; acc[6] += e*vb.z; acc[7] += e*vb.w;
                    }
                }
#pragma unroll
                for (int m = 1; m <= 4; m <<= 1) {
                    ssum += __shfl_xor(ssum, m, 8);
#pragma unroll
                    for (int d = 0; d < 8; ++d) acc[d] += __shfl_xor(acc[d], m, 8);
                }
                if (lg == 0) {
#pragma unroll
                    for (int d = 0; d < 8; ++d) upd[j*STR + d] = acc[d] / ssum;
                }
            }
        } else {
            const int m64 = t & 63;
            constexpr int NK64 = (L + 63) / 64;
            float vacc[8] = {0,0,0,0,0,0,0,0};
            float acc[8]  = {0,0,0,0,0,0,0,0};
            float ssum = 0.f;
            float pk[NK64];
            float mx = -INFINITY;
            float4 qa = make_float4(0,0,0,0), qb4 = make_float4(0,0,0,0);
            if constexpr (U > 24) {
                qa  = *(const float4*)&q_sel[24*STR];
                qb4 = *(const float4*)&q_sel[24*STR+4];
            }
#pragma unroll
            for (int k = 0; k < NK64; ++k) {
                const int l = m64 + 64*k;
                float s = -INFINITY;
                if constexpr (U > 24) {
                    if (l < L) {
                        const float4 ka = *(const float4*)&ks[l*STR];
                        const float4 kb = *(const float4*)&ks[l*STR+4];
                        s = dot8(qa, qb4, ka, kb) * 0.35355339059327373f;
                    }
                }
                pk[k] = s;
                mx = fmaxf(mx, s);
            }
            if constexpr (U > 24) {
#pragma unroll
                for (int m = 1; m <= 32; m <<= 1) mx = fmaxf(mx, __shfl_xor(mx, m));
            }
#pragma unroll
            for (int k = 0; k < NK64; ++k) {
                const int l = m64 + 64*k;
                if (l < L) {
                    const float4 va = *(const float4*)&vs[l*STR];
                    const float4 vb = *(const float4*)&vs[l*STR+4];
                    vacc[0] += va.x; vacc[1] += va.y; vacc[2] += va.z; vacc[3] += va.w;
                    vacc[4] += vb.x; vacc[5] += vb.y; vacc[6] += vb.z; vacc[7] += vb.w;
                    if constexpr (U > 24) {
                        const float e = __expf(pk[k] - mx);
                        ssum += e;
                        acc[0] += e*va.x; acc[1] += e*va.y; acc[2] += e*va.z; acc[3] += e*va.w;
                        acc[4] += e*vb.x; acc[5] += e*vb.y; acc[6] += e*vb.z; acc[7] += e*vb.w;
                    }
                }
            }
#pragma unroll
            for (int m = 1; m <= 32; m <<= 1) {
#pragma unroll
                for (int d = 0; d < 8; ++d) vacc[d] += __shfl_xor(vacc[d], m);
                if constexpr (U > 24) {
                    ssum += __shfl_xor(ssum, m);
#pragma unroll
                    for (int d = 0; d < 8; ++d) acc[d] += __shfl_xor(acc[d], m);
                }
            }
            if (m64 == 0) {
#pragma unroll
                for (int d = 0; d < 8; ++d) vmean[d] = vacc[d] / (float)L;
                if constexpr (U > 24) {
#pragma unroll
                    for (int d = 0; d < 8; ++d) upd[24*STR + d] = acc[d] / ssum;
                }
            }
        }
    }
    __syncthreads();

    // ---- ctx -> @ow+ob -> residual+LN1 -> FF -> residual+LN2 (+softpool score)
    if (t < L) {
        float ctx[8];
        if (sj >= 0) {
            const float4 ua = *(const float4*)&upd[sj*STR];
            const float4 ub4 = *(const float4*)&upd[sj*STR+4];
            ctx[0]=ua.x; ctx[1]=ua.y; ctx[2]=ua.z; ctx[3]=ua.w;
            ctx[4]=ub4.x; ctx[5]=ub4.y; ctx[6]=ub4.z; ctx[7]=ub4.w;
        } else {
            const float4 va = *(const float4*)&vmean[0];
            const float4 vb = *(const float4*)&vmean[4];
            ctx[0]=va.x; ctx[1]=va.y; ctx[2]=va.z; ctx[3]=va.w;
            ctx[4]=vb.x; ctx[5]=vb.y; ctx[6]=vb.z; ctx[7]=vb.w;
        }
        float xr[8];
#pragma unroll
        for (int dd = 0; dd < 8; ++dd) {
            float acc = 0.f;
#pragma unroll
            for (int e = 0; e < 8; ++e) acc += ctx[e] * ow[e*8+dd];
            xr[dd] = hrr[dd] + (acc + ob[dd]);
        }
        float mean = 0.f;
#pragma unroll
        for (int e = 0; e < 8; ++e) mean += xr[e];
        mean *= 0.125f;
        float var = 0.f;
#pragma unroll
        for (int e = 0; e < 8; ++e) { const float z = xr[e] - mean; var += z*z; }
        var *= 0.125f;
        float inv = 1.0f / sqrtf(var + 1e-5f);
        float y[8];
#pragma unroll
        for (int e = 0; e < 8; ++e) y[e] = (xr[e] - mean) * inv * g1[e] + bb1[e];

        float f1[12];
#pragma unroll
        for (int o = 0; o < 12; ++o) {
            float acc = 0.f;
#pragma unroll
            for (int e = 0; e < 8; ++e) acc += y[e] * f1w[e*12+o];
            f1[o] = fmaxf(acc + f1b[o], 0.f);
        }
        float x2[8];
#pragma unroll
        for (int o = 0; o < 8; ++o) {
            float acc = 0.f;
#pragma unroll
            for (int e = 0; e < 12; ++e) acc += f1[e] * f2w[e*8+o];
            x2[o] = y[o] + (acc + f2b[o]);
        }
        mean = 0.f;
#pragma unroll
        for (int e = 0; e < 8; ++e) mean += x2[e];
        mean *= 0.125f;
        var = 0.f;
#pragma unroll
        for (int e = 0; e < 8; ++e) { const float z = x2[e] - mean; var += z*z; }
        var *= 0.125f;
        inv = 1.0f / sqrtf(var + 1e-5f);
        float y2[8];
#pragma unroll
        for (int e = 0; e < 8; ++e) y2[e] = (x2[e] - mean) * inv * g2[e] + bb2[e];
        *(float4*)&h[t*STR]   = make_float4(y2[0],y2[1],y2[2],y2[3]);
        *(float4*)&h[t*STR+4] = make_float4(y2[4],y2[5],y2[6],y2[7]);

        if (POOL) {     // softpool score from registers; keys region is dead
            float acc2 = 0.f;
#pragma unroll
            for (int o = 0; o < 12; ++o) {
                float acc = 0.f;
#pragma unroll
                for (int e = 0; e < 8; ++e) acc += y2[e] * spw1[e*12+o];
                acc2 += fmaxf(acc + spb1[o], 0.f) * spw2[o];
            }
            ((float*)keys)[t] = acc2 + spb2[0];
        }
    }
    __syncthreads();

    // ---- softpool combine
    if (POOL) {
        constexpr int Lh = L / 2;
        float nrow[8];
        const float* spsc = (const float*)keys;
        if (t < Lh) {
            const float2 ss = *(const float2*)&spsc[2*t];
            const float m = fmaxf(ss.x, ss.y);
            const float e0 = __expf(ss.x - m), e1 = __expf(ss.y - m);
            const float den = e0 + e1;
            const float w0 = e0 / den, w1 = e1 / den;
            const float4 a0 = *(const float4*)&h[(2*t)*STR];
            const float4 a1 = *(const float4*)&h[(2*t)*STR+4];
            const float4 b0 = *(const float4*)&h[(2*t+1)*STR];
            const float4 b1 = *(const float4*)&h[(2*t+1)*STR+4];
            nrow[0] = w0*a0.x + w1*b0.x; nrow[1] = w0*a0.y + w1*b0.y;
            nrow[2] = w0*a0.z + w1*b0.z; nrow[3] = w0*a0.w + w1*b0.w;
            nrow[4] = w0*a1.x + w1*b1.x; nrow[5] = w0*a1.y + w1*b1.y;
            nrow[6] = w0*a1.z + w1*b1.z; nrow[7] = w0*a1.w + w1*b1.w;
        }
        __syncthreads();
        if (t < Lh) {
            *(float4*)&h[t*STR]   = make_float4(nrow[0],nrow[1],nrow[2],nrow[3]);
            *(float4*)&h[t*STR+4] = make_float4(nrow[4],nrow[5],nrow[6],nrow[7]);
        }
        __syncthreads();
    }
}

__global__ __launch_bounds__(256, 4) void fused_forward(Params p) {
    const int b = blockIdx.x;
    const int t = threadIdx.x;

    __shared__ __align__(16) float h [148 * STR];
    __shared__ __align__(16) float ks[148 * STR];
    __shared__ __align__(16) float vs[148 * STR];
    __shared__ __align__(16) unsigned long long keys[150];   // also softpool scores
    __shared__ __align__(16) float q_sel[25 * STR];          // also head hd2
    __shared__ __align__(16) float upd[25 * STR];
    __shared__ __align__(16) float vmean[8];
    __shared__ int   ntop;
    __shared__ float scale_s;
    __shared__ float smx[4], smn[4];

    // ---- global-scale reduce: part has 256 x {mx, mn}
    {
        float mx = p.part[2*t], mn = p.part[2*t+1];
#pragma unroll
        for (int o = 32; o; o >>= 1) {
            mx = fmaxf(mx, __shfl_xor(mx, o));
            mn = fminf(mn, __shfl_xor(mn, o));
        }
        if ((t & 63) == 0) { smx[t >> 6] = mx; smn[t >> 6] = mn; }
        __syncthreads();
        if (t == 0) {
            for (int w = 1; w < 4; ++w) { mx = fmaxf(mx, smx[w]); mn = fminf(mn, smn[w]); }
            scale_s = mx - mn + 1e-6f;
        }
        __syncthreads();
    }
    const float dscale = scale_s;

    // ---- preprocess: pair-mean of [x, x/scale], sin/cos pe, @pe_w + pe_b
    if (t < 148) {
        const float2 xp = ((const float2*)(p.x + b * 296))[t];
        float pin[4];
        pin[0] = 0.5f * (xp.x + xp.y);
        pin[1] = 0.5f * (xp.x / dscale + xp.y / dscale);
        pin[2] = sinf((float)t);
        pin[3] = cosf((float)t);
        float o[8];
#pragma unroll
        for (int dd = 0; dd < 8; ++dd) {
            float acc = 0.f;
#pragma unroll
            for (int e = 0; e < 4; ++e) acc += pin[e] * p.pe_w[e*8+dd];
            o[dd] = acc + p.pe_b[dd];
        }
        *(float4*)&h[t*STR]   = make_float4(o[0],o[1],o[2],o[3]);
        *(float4*)&h[t*STR+4] = make_float4(o[4],o[5],o[6],o[7]);
    }
    __syncthreads();

    layer_fn<148, 25, 25, true >(t, h, ks, vs, keys, q_sel, upd, vmean, &ntop,
        p.qw,       p.qb,       p.kw,       p.kb,       p.vw,       p.vb,       p.ow,       p.ob,
        p.f1w,      p.f1b,      p.f2w,      p.f2b,
        p.ln1g,     p.ln1b,     p.ln2g,     p.ln2b,     p.samp1,
        p.sp1w1, p.sp1b1, p.sp1w2, p.sp1b2);
    layer_fn<74, 25, 25, true >(t, h, ks, vs, keys, q_sel, upd, vmean, &ntop,
        p.qw + 64,  p.qb + 8,   p.kw + 64,  p.kb + 8,   p.vw + 64,  p.vb + 8,   p.ow + 64,  p.ob + 8,
        p.f1w + 96, p.f1b + 12, p.f2w + 96, p.f2b + 8,
        p.ln1g + 8, p.ln1b + 8, p.ln2g + 8, p.ln2b + 8, p.samp2,
        p.sp2w1, p.sp2b1, p.sp2w2, p.sp2b2);
    layer_fn<37, 20, 20, false>(t, h, ks, vs, keys, q_sel, upd, vmean, &ntop,
        p.qw + 128, p.qb + 16,  p.kw + 128, p.kb + 16,  p.vw + 128, p.vb + 16,  p.ow + 128, p.ob + 16,
        p.f1w + 192, p.f1b + 24, p.f2w + 192, p.f2b + 16,
        p.ln1g + 16, p.ln1b + 16, p.ln2g + 16, p.ln2b + 16, p.samp3,
        nullptr, nullptr, nullptr, nullptr);

    // ---- head: (37,8)@dr_w -> flat 148 -> fc1(74) relu -> fc2(37) relu -> fo -> sigmoid
    float* hf  = ks;              // 148 floats (ks dead)
    float* s1  = vs;              // 74 floats (vs dead)
    float* hd2 = (float*)q_sel;   // 37 floats (q_sel dead)
    if (t < 37) {
        const float4 ya = *(const float4*)&h[t*STR];
        const float4 yb = *(const float4*)&h[t*STR+4];
        float o[4];
#pragma unroll
        for (int c = 0; c < 4; ++c) {
            float acc = ya.x*p.dr_w[0*4+c] + ya.y*p.dr_w[1*4+c]
                      + ya.z*p.dr_w[2*4+c] + ya.w*p.dr_w[3*4+c]
                      + yb.x*p.dr_w[4*4+c] + yb.y*p.dr_w[5*4+c]
                      + yb.z*p.dr_w[6*4+c] + yb.w*p.dr_w[7*4+c];
            o[c] = acc + p.dr_b[c];
        }
        *(float4*)&hf[t*4] = make_float4(o[0],o[1],o[2],o[3]);
    }
    __syncthreads();
    if (t < 74) {
        float acc = 0.f;
#pragma unroll 4
        for (int i4 = 0; i4 < 37; ++i4) {
            const float4 hv = *(const float4*)&hf[i4*4];
            const int i = i4 * 4;
            acc += hv.x * p.fc1w[(i  )*74 + t] + hv.y * p.fc1w[(i+1)*74 + t]
                 + hv.z * p.fc1w[(i+2)*74 + t] + hv.w * p.fc1w[(i+3)*74 + t];
        }
        s1[t] = fmaxf(acc + p.fc1b[t], 0.f);
    }
    __syncthreads();
    if (t < 37) {
        float acc = 0.f;
#pragma unroll 2
        for (int i = 0; i < 74; ++i) acc += s1[i] * p.fc2w[i*37 + t];
        hd2[t] = fmaxf(acc + p.fc2b[t], 0.f);
    }
    __syncthreads();
    if (t == 0) {
        float acc = 0.f;
        for (int i = 0; i < 37; ++i) acc += hd2[i] * p.fow[i];
        p.out[b] = 1.f / (1.f + __expf(-(acc + p.fob[0])));
    }
}

extern "C" void kernel_launch(void* const* d_in, const int* in_sizes, int n_in,
                              void* d_out, int out_size, void* d_ws, size_t ws_size,
                              hipStream_t stream) {
    Params p;
    p.x     = (const float*)d_in[0];
    p.samp1 = (const int*)d_in[1];
    p.samp2 = (const int*)d_in[2];
    p.samp3 = (const int*)d_in[3];
    p.pe_w  = (const float*)d_in[4];  p.pe_b  = (const float*)d_in[5];
    p.qw    = (const float*)d_in[6];  p.qb    = (const float*)d_in[7];
    p.kw    = (const float*)d_in[8];  p.kb    = (const float*)d_in[9];
    p.vw    = (const float*)d_in[10]; p.vb    = (const float*)d_in[11];
    p.ow    = (const float*)d_in[12]; p.ob    = (const float*)d_in[13];
    p.f1w   = (const float*)d_in[14]; p.f1b   = (const float*)d_in[15];
    p.f2w   = (const float*)d_in[16]; p.f2b   = (const float*)d_in[17];
    p.ln1g  = (const float*)d_in[18]; p.ln1b  = (const float*)d_in[19];
    p.ln2g  = (const float*)d_in[20]; p.ln2b  = (const float*)d_in[21];
    p.sp1w1 = (const float*)d_in[22]; p.sp1b1 = (const float*)d_in[23];
    p.sp1w2 = (const float*)d_in[24]; p.sp1b2 = (const float*)d_in[25];
    p.sp2w1 = (const float*)d_in[26]; p.sp2b1 = (const float*)d_in[27];
    p.sp2w2 = (const float*)d_in[28]; p.sp2b2 = (const float*)d_in[29];
    p.dr_w  = (const float*)d_in[30]; p.dr_b  = (const float*)d_in[31];
    p.fc1w  = (const float*)d_in[32]; p.fc1b  = (const float*)d_in[33];
    p.fc2w  = (const float*)d_in[34]; p.fc2b  = (const float*)d_in[35];
    p.fow   = (const float*)d_in[36]; p.fob   = (const float*)d_in[37];

    const int n = in_sizes[0];          // 4096 * 296
    const int B = n / 296;

    float* part = (float*)d_ws;         // 512 floats: 256 blocks x {max, min}

    minmax_part<<<256, 256, 0, stream>>>((const float4*)p.x, n / 4, part);

    p.part = part;
    p.out  = (float*)d_out;
    fused_forward<<<B, 256, 0, stream>>>(p);
}